// Round 1
// baseline (1087.192 us; speedup 1.0000x reference)
//
#include <hip/hip_runtime.h>

// GANLoss: out = -mean(prob[n, targets[n]] * reward[n]) over N rows.
// N=8192, C=32000. Gather-latency / launch-overhead bound; double-precision
// accumulation so the per-block atomic ordering is numerically irrelevant.

__global__ void ganloss_partial(const float* __restrict__ prob,
                                const int* __restrict__ targets,
                                const float* __restrict__ reward,
                                double* __restrict__ acc,
                                int N, int C) {
    int i = blockIdx.x * blockDim.x + threadIdx.x;
    double v = 0.0;
    if (i < N) {
        int t = targets[i];
        v = (double)prob[(size_t)i * (size_t)C + (size_t)t] * (double)reward[i];
    }
    // wave64 shuffle reduction
    #pragma unroll
    for (int off = 32; off > 0; off >>= 1)
        v += __shfl_down(v, off, 64);

    __shared__ double wsum[4];  // 256 threads = 4 waves
    int wave = threadIdx.x >> 6;
    int lane = threadIdx.x & 63;
    if (lane == 0) wsum[wave] = v;
    __syncthreads();
    if (threadIdx.x == 0) {
        double s = wsum[0] + wsum[1] + wsum[2] + wsum[3];
        atomicAdd(acc, s);  // device-scope f64 atomic, fine across XCDs
    }
}

__global__ void ganloss_finalize(const double* __restrict__ acc,
                                 float* __restrict__ out, int N) {
    out[0] = (float)(-acc[0] / (double)N);
}

extern "C" void kernel_launch(void* const* d_in, const int* in_sizes, int n_in,
                              void* d_out, int out_size, void* d_ws, size_t ws_size,
                              hipStream_t stream) {
    const float* prob    = (const float*)d_in[0];
    const int*   targets = (const int*)  d_in[1];
    const float* reward  = (const float*)d_in[2];
    float* out = (float*)d_out;

    int N = in_sizes[1];               // targets is (N,)
    int C = in_sizes[0] / N;           // prob is (N, C)

    double* acc = (double*)d_ws;
    hipMemsetAsync(acc, 0, sizeof(double), stream);  // ws is poisoned 0xAA each call

    int block = 256;
    int grid = (N + block - 1) / block;  // 32 blocks
    ganloss_partial<<<grid, block, 0, stream>>>(prob, targets, reward, acc, N, C);
    ganloss_finalize<<<1, 1, 0, stream>>>(acc, out, N);
}